// Round 1
// baseline (227.969 us; speedup 1.0000x reference)
//
#include <hip/hip_runtime.h>

// DataPreprocessor: interleave even/odd row planes then extract 16x16 patches.
// out[b, z1*32+z2, p*16+q] = in[b, r&1, (r>>1)*512 + c],  r = 16*z1+p, c = 16*z2+q.
//
// v2: LDS-staged tile version. One block per (b, z1) row-group:
//   - input  = two contiguous 16 KiB chunks (8 rows x 2 KiB from each plane)
//   - output = one contiguous 32 KiB chunk (patches z1*32 .. z1*32+31)
// Both global phases are fully coalesced (1 KiB per wave per instruction),
// vs. the v1 direct copy whose read side was a 64 B-granule gather across
// 16 scattered segments per wave (~1.5x off the copy roofline).
//
// LDS layout: float4 tile [16 rows][128 cols], XOR-swizzled:
//   a4 = r*128 + (c4 ^ ((r&7)<<2))
// Write phase: wave = 64 consecutive c4, fixed r  -> 64 distinct float4 in a
//   1 KiB span -> 8 bank phases, conflict-free.
// Read phase:  lane L reads (p = L>>2, q4 = L&3), z2 fixed per wave ->
//   bank group = (parity-ish of z2^p)*16 + q4*4; each 8-lane group covers all
//   32 banks once -> 8 phases, conflict-free. Same XOR on both sides.

__global__ __launch_bounds__(256) void DataPreprocessor_60739427500336_kernel(
    const float4* __restrict__ in, float4* __restrict__ out) {
    __shared__ float4 lds[2048];  // 32 KiB: 16 rows x 128 float4

    const int tid  = threadIdx.x;
    const int tile = blockIdx.x;      // b*16 + z1
    const int z1   = tile & 15;
    const int b    = tile >> 4;

    // float4 indexing: input per-b = 32768 f4 (plane stride 16384 f4, row = 128 f4)
    // output per-b = 32768 f4, per-tile = 32 patches * 64 f4 = 2048 f4.
    const int in_base  = (b << 15) + (z1 << 10);  // plane-0 chunk: rows 8*z1 .. 8*z1+7
    const int out_base = (b << 15) + (z1 << 11);

    // ---- Load: global -> LDS (interleave rows, apply swizzle) ----
    #pragma unroll
    for (int s = 0; s < 8; ++s) {
        int i4     = tid + (s << 8);        // 0..2047
        int parity = i4 >> 10;              // first 1024 f4 = plane 0, next = plane 1
        int off    = i4 & 1023;             // within the 16 KiB plane chunk
        int j      = off >> 7;              // local source row 0..7
        int c4     = off & 127;             // col in float4 units
        int r      = (j << 1) + parity;     // interleaved row 0..15 (R-row = 16*z1 + r)
        int a4     = (r << 7) + (c4 ^ ((r & 7) << 2));
        lds[a4] = in[in_base + (parity << 14) + off];
    }
    __syncthreads();

    // ---- Store: LDS -> global (contiguous 32 KiB out chunk) ----
    #pragma unroll
    for (int s = 0; s < 8; ++s) {
        int o4 = tid + (s << 8);            // 0..2047 within tile
        int q4 = o4 & 3;                    // q/4
        int p  = (o4 >> 2) & 15;
        int z2 = (o4 >> 6) & 31;
        int a4 = (p << 7) + ((((z2 << 2) + q4)) ^ ((p & 7) << 2));
        out[out_base + o4] = lds[a4];
    }
}

extern "C" void kernel_launch(void* const* d_in, const int* in_sizes, int n_in,
                              void* d_out, int out_size, void* d_ws, size_t ws_size,
                              hipStream_t stream) {
    const float4* in = (const float4*)d_in[0];
    float4* out = (float4*)d_out;
    // One block per (b, z1): 256 * 16 = 4096 blocks, 32 KiB LDS each
    // (160 KiB/CU -> 5 blocks/CU; memory-bound, ample occupancy).
    const int grid = 256 * 16;
    const int block = 256;
    DataPreprocessor_60739427500336_kernel<<<grid, block, 0, stream>>>(in, out);
}